// Round 13
// baseline (196.747 us; speedup 1.0000x reference)
//
#include <hip/hip_runtime.h>
#include <hip/hip_bf16.h>
#include <cstdint>
#include <cstddef>

#define BB 4
#define TT 4096
#define HH 16
#define NROWS 16384  // B*T

typedef __attribute__((ext_vector_type(8))) short bf16x8;
typedef __attribute__((ext_vector_type(4))) float f32x4;

__device__ __forceinline__ void gload_lds16(const void* g, void* l) {
  __builtin_amdgcn_global_load_lds(
      (const __attribute__((address_space(1))) void*)g,
      (__attribute__((address_space(3))) void*)l, 16, 0, 0);
}

template <int N>
__device__ __forceinline__ void wait_vmcnt() {
  if constexpr (N == 4)
    asm volatile("s_waitcnt vmcnt(4)" ::: "memory");
  else
    asm volatile("s_waitcnt vmcnt(0)" ::: "memory");
  __builtin_amdgcn_sched_barrier(0);
}

__device__ __forceinline__ void hbar() {
  asm volatile("s_barrier" ::: "memory");
  __builtin_amdgcn_sched_barrier(0);
}

// ---------------------------------------------------------------------------
// prep: fused x->bf16 conversion (blocks 0..8191) + W transpose (8192..9215)
// ---------------------------------------------------------------------------
__global__ __launch_bounds__(256) void prep_k(const float* __restrict__ x,
                                              const float* __restrict__ Wq,
                                              const float* __restrict__ Wk,
                                              const float* __restrict__ Wv,
                                              const float* __restrict__ Wo,
                                              __hip_bfloat16* __restrict__ xb,
                                              __hip_bfloat16* __restrict__ WT) {
  const int t = threadIdx.x;
  if (blockIdx.x < 8192) {
    const size_t i = ((size_t)blockIdx.x * 256 + t) * 8;
    float4 a = *(const float4*)&x[i];
    float4 b = *(const float4*)&x[i + 4];
    __hip_bfloat16 o[8] __attribute__((aligned(16)));
    o[0] = __float2bfloat16(a.x); o[1] = __float2bfloat16(a.y);
    o[2] = __float2bfloat16(a.z); o[3] = __float2bfloat16(a.w);
    o[4] = __float2bfloat16(b.x); o[5] = __float2bfloat16(b.y);
    o[6] = __float2bfloat16(b.z); o[7] = __float2bfloat16(b.w);
    *(int4*)&xb[i] = *(const int4*)o;
    return;
  }
  const int bid2 = blockIdx.x - 8192;
  const int which = bid2 >> 8;
  const int sub = bid2 & 255;
  const float* W = which == 0 ? Wq : which == 1 ? Wk : which == 2 ? Wv : Wo;
  __shared__ float tile[64][65];
  const int n0 = (sub & 15) * 64, k0 = (sub >> 4) * 64;
  const int r = t >> 2;
  const int cq = (t & 3) * 16;
#pragma unroll
  for (int i = 0; i < 4; ++i) {
    float4 v = *(const float4*)&W[(size_t)(k0 + r) * 1024 + n0 + cq + i * 4];
    tile[r][cq + i * 4 + 0] = v.x;
    tile[r][cq + i * 4 + 1] = v.y;
    tile[r][cq + i * 4 + 2] = v.z;
    tile[r][cq + i * 4 + 3] = v.w;
  }
  __syncthreads();
  __hip_bfloat16 ob[16] __attribute__((aligned(16)));
#pragma unroll
  for (int j = 0; j < 16; ++j) ob[j] = __float2bfloat16(tile[cq + j][r]);
  __hip_bfloat16* dst = WT + (size_t)(which * 1024 + n0 + r) * 1024 + k0 + cq;
  *(int4*)dst = *(const int4*)&ob[0];
  *(int4*)(dst + 8) = *(const int4*)&ob[8];
}

// ---------------------------------------------------------------------------
// EXPERIMENT (round-13): MFMA bf16 GEMM, 256x256 tile, BK=32, dbuf 64 KB LDS
// -> 2 blocks/CU (4 waves/SIMD) vs champion's 1 block/CU. Same verified
// octet-rotation layout / reads / epilogue as mgemm3. One barrier per kstep
// (32 total, same as champion). Ledger: stage(u+1)->buf[(u+1)&1] whose reads
// (kstep u-1) completed before the previous barrier; own vmcnt(0) then
// s_barrier => all waves' stage(u+1) landed before reads(u+1).
// ---------------------------------------------------------------------------
template <int OMODE, int PB>
__global__ __launch_bounds__(512) void mgemm6_k(
    const __hip_bfloat16* __restrict__ A, int lda,
    const __hip_bfloat16* __restrict__ BT, const float* __restrict__ bias,
    void* __restrict__ Cp, int ldc, int gx) {
  __shared__ __hip_bfloat16 lds[2][16384];  // 64 KiB: A 8192 | B 8192 / buf

  const int t = threadIdx.x;
  const int wid = t >> 6, l = t & 63;
  const int wr = wid >> 2, wc = wid & 3;

  const int nwg = gridDim.x;
  const int cpx = nwg >> 3;
  const int bid = blockIdx.x;
  const int swz = (bid & 7) * cpx + (bid >> 3);
  const int bx = swz % gx, by = swz / gx;
  const int row0 = by * 256, col0 = bx * 256;

  const __hip_bfloat16* BTb = PB ? BT + ((size_t)(row0 >> 12) << 20) : BT;

  const int sg = l >> 3;
  const int octp = ((l & 7) + sg) & 7;
  const int koct = octp & 3;
  const int srow = 2 * (wid * 16 + sg) + (octp >> 2);
  const __hip_bfloat16* As0 = A + (size_t)(row0 + srow) * lda + koct * 8;
  const __hip_bfloat16* Bs0 = BTb + (size_t)(col0 + srow) * 1024 + koct * 8;

  f32x4 acc[8][4];
#pragma unroll
  for (int m = 0; m < 8; ++m)
#pragma unroll
    for (int n = 0; n < 4; ++n) acc[m][n] = (f32x4){0.f, 0.f, 0.f, 0.f};

  const int lr = l & 15, hk = l >> 4;
  const int slot = (((lr & 1) << 2) + hk - (lr >> 1)) & 7;
  const int rdo = (lr >> 1) * 64 + slot * 8;

  auto stage = [&](int u) {
    __hip_bfloat16* d = &lds[u & 1][wid * 1024];
    const __hip_bfloat16* sa = As0 + u * 32;
    const __hip_bfloat16* sb = Bs0 + u * 32;
    gload_lds16(sa, d);
    gload_lds16(sa + (size_t)16 * lda, d + 512);
    gload_lds16(sb, d + 8192);
    gload_lds16(sb + (size_t)16 * 1024, d + 8192 + 512);
  };

  stage(0);
  wait_vmcnt<0>();
  hbar();

  for (int u = 0; u < 32; ++u) {
    if (u < 31) stage(u + 1);
    const __hip_bfloat16* s = &lds[u & 1][0];
    bf16x8 bfv[4], afv[4];
#pragma unroll
    for (int n = 0; n < 4; ++n)
      bfv[n] = *(const bf16x8*)(s + 8192 + wc * 2048 + n * 512 + rdo);
#pragma unroll
    for (int j = 0; j < 4; ++j)
      afv[j] = *(const bf16x8*)(s + wr * 4096 + j * 512 + rdo);
    __builtin_amdgcn_s_setprio(1);
#pragma unroll
    for (int j = 0; j < 4; ++j)
#pragma unroll
      for (int n = 0; n < 4; ++n)
        acc[j][n] = __builtin_amdgcn_mfma_f32_16x16x32_bf16(afv[j], bfv[n],
                                                            acc[j][n], 0, 0, 0);
    __builtin_amdgcn_s_setprio(0);
#pragma unroll
    for (int j = 0; j < 4; ++j)
      afv[j] = *(const bf16x8*)(s + wr * 4096 + 2048 + j * 512 + rdo);
    __builtin_amdgcn_s_setprio(1);
#pragma unroll
    for (int j = 0; j < 4; ++j)
#pragma unroll
      for (int n = 0; n < 4; ++n)
        acc[4 + j][n] = __builtin_amdgcn_mfma_f32_16x16x32_bf16(
            afv[j], bfv[n], acc[4 + j][n], 0, 0, 0);
    __builtin_amdgcn_s_setprio(0);
    if (u < 31) {
      wait_vmcnt<0>();
      hbar();
    }
  }

  const int cr = hk * 4;
  const int cc = lr;
  if constexpr (OMODE == 0) {
    __hip_bfloat16* C = (__hip_bfloat16*)Cp;
#pragma unroll
    for (int m = 0; m < 8; ++m)
#pragma unroll
      for (int n = 0; n < 4; ++n) {
        const size_t cb = (size_t)(row0 + wr * 128 + m * 16 + cr) * ldc +
                          col0 + wc * 64 + n * 16 + cc;
#pragma unroll
        for (int j = 0; j < 4; ++j)
          C[cb + (size_t)j * ldc] = __float2bfloat16(acc[m][n][j]);
      }
  } else {
    float* C = (float*)Cp;
    float bv[4];
#pragma unroll
    for (int n = 0; n < 4; ++n) bv[n] = bias[col0 + wc * 64 + n * 16 + cc];
#pragma unroll
    for (int m = 0; m < 8; ++m)
#pragma unroll
      for (int n = 0; n < 4; ++n) {
        const size_t cb = (size_t)(row0 + wr * 128 + m * 16 + cr) * ldc +
                          col0 + wc * 64 + n * 16 + cc;
#pragma unroll
        for (int j = 0; j < 4; ++j)
          C[cb + (size_t)j * ldc] = acc[m][n][j] + bv[n];
      }
  }
}

// ---------------------------------------------------------------------------
// CONTROL: champion mgemm3 (round-7 schedule verbatim; 106 us QKV-equiv).
// Used for the out-GEMM this round as the in-run A/B reference.
// ---------------------------------------------------------------------------
template <int OMODE, int PB>
__global__ __launch_bounds__(512) void mgemm3_k(
    const __hip_bfloat16* __restrict__ A, int lda,
    const __hip_bfloat16* __restrict__ BT, const float* __restrict__ bias,
    void* __restrict__ Cp, int ldc, int gx) {
  __shared__ __hip_bfloat16 lds[2][32768];  // 128 KiB

  const int t = threadIdx.x;
  const int wid = t >> 6, l = t & 63;
  const int wr = wid >> 2, wc = wid & 3;

  const int nwg = gridDim.x;
  const int cpx = nwg >> 3;
  const int bid = blockIdx.x;
  const int swz = (bid & 7) * cpx + (bid >> 3);
  const int bx = swz % gx, by = swz / gx;
  const int row0 = by * 256, col0 = bx * 256;

  const __hip_bfloat16* BTb = PB ? BT + ((size_t)(row0 >> 12) << 20) : BT;

  const int sg = l >> 3;
  const int octp = ((l & 7) + sg) & 7;
  const int koct = octp & 3;
  const int srow = 2 * (wid * 16 + sg) + (octp >> 2);
  const __hip_bfloat16* As0 = A + (size_t)(row0 + srow) * lda + koct * 8;
  const __hip_bfloat16* Bs0 = BTb + (size_t)(col0 + srow) * 1024 + koct * 8;

  f32x4 acc[8][4];
#pragma unroll
  for (int m = 0; m < 8; ++m)
#pragma unroll
    for (int n = 0; n < 4; ++n) acc[m][n] = (f32x4){0.f, 0.f, 0.f, 0.f};

  const int lr = l & 15, hk = l >> 4;
  const int slot = (((lr & 1) << 2) + hk - (lr >> 1)) & 7;
  const int rdo = (lr >> 1) * 64 + slot * 8;

  auto stageA = [&](int tn, int c) {
    __hip_bfloat16* d = &lds[tn & 1][c * 8192 + wid * 1024];
    const __hip_bfloat16* s = As0 + tn * 64 + c * 32;
    gload_lds16(s, d);
    gload_lds16(s + (size_t)16 * lda, d + 512);
  };
  auto stageB = [&](int tn, int c) {
    __hip_bfloat16* d = &lds[tn & 1][16384 + c * 8192 + wid * 1024];
    const __hip_bfloat16* s = Bs0 + tn * 64 + c * 32;
    gload_lds16(s, d);
    gload_lds16(s + (size_t)16 * 1024, d + 512);
  };

  stageA(0, 0); stageB(0, 0); stageA(0, 1); stageB(0, 1);

  const __hip_bfloat16* sb = &lds[0][0];
  for (int tn = 0; tn < 16; ++tn) {
    const int bufo = (tn & 1) * 32768;
    const bool pre = tn < 15;
    bf16x8 bfv[4], afv[4];

    // ===== kstep 0 =====
    wait_vmcnt<4>();
    hbar();
    if (pre) stageA(tn + 1, 0);
#pragma unroll
    for (int n = 0; n < 4; ++n)
      bfv[n] = *(const bf16x8*)(sb + bufo + 16384 + wc * 2048 + n * 512 + rdo);
#pragma unroll
    for (int j = 0; j < 4; ++j)
      afv[j] = *(const bf16x8*)(sb + bufo + wr * 4096 + j * 512 + rdo);
    __builtin_amdgcn_s_setprio(1);
#pragma unroll
    for (int j = 0; j < 4; ++j)
#pragma unroll
      for (int n = 0; n < 4; ++n)
        acc[j][n] = __builtin_amdgcn_mfma_f32_16x16x32_bf16(afv[j], bfv[n],
                                                            acc[j][n], 0, 0, 0);
    __builtin_amdgcn_s_setprio(0);
    if (pre) stageB(tn + 1, 0);
#pragma unroll
    for (int j = 0; j < 4; ++j)
      afv[j] = *(const bf16x8*)(sb + bufo + wr * 4096 + 2048 + j * 512 + rdo);
    __builtin_amdgcn_s_setprio(1);
#pragma unroll
    for (int j = 0; j < 4; ++j)
#pragma unroll
      for (int n = 0; n < 4; ++n)
        acc[4 + j][n] = __builtin_amdgcn_mfma_f32_16x16x32_bf16(
            afv[j], bfv[n], acc[4 + j][n], 0, 0, 0);
    __builtin_amdgcn_s_setprio(0);

    // ===== kstep 1 =====
    if (pre)
      wait_vmcnt<4>();
    else
      wait_vmcnt<0>();
    hbar();
    if (pre) stageA(tn + 1, 1);
#pragma unroll
    for (int n = 0; n < 4; ++n)
      bfv[n] = *(const bf16x8*)(sb + bufo + 8192 + 16384 + wc * 2048 +
                                n * 512 + rdo);
#pragma unroll
    for (int j = 0; j < 4; ++j)
      afv[j] = *(const bf16x8*)(sb + bufo + 8192 + wr * 4096 + j * 512 + rdo);
    __builtin_amdgcn_s_setprio(1);
#pragma unroll
    for (int j = 0; j < 4; ++j)
#pragma unroll
      for (int n = 0; n < 4; ++n)
        acc[j][n] = __builtin_amdgcn_mfma_f32_16x16x32_bf16(afv[j], bfv[n],
                                                            acc[j][n], 0, 0, 0);
    __builtin_amdgcn_s_setprio(0);
    if (pre) stageB(tn + 1, 1);
#pragma unroll
    for (int j = 0; j < 4; ++j)
      afv[j] = *(const bf16x8*)(sb + bufo + 8192 + wr * 4096 + 2048 + j * 512 +
                                rdo);
    __builtin_amdgcn_s_setprio(1);
#pragma unroll
    for (int j = 0; j < 4; ++j)
#pragma unroll
      for (int n = 0; n < 4; ++n)
        acc[4 + j][n] = __builtin_amdgcn_mfma_f32_16x16x32_bf16(
            afv[j], bfv[n], acc[4 + j][n], 0, 0, 0);
    __builtin_amdgcn_s_setprio(0);
  }

  const int cr = hk * 4;
  const int cc = lr;
  if constexpr (OMODE == 0) {
    __hip_bfloat16* C = (__hip_bfloat16*)Cp;
#pragma unroll
    for (int m = 0; m < 8; ++m)
#pragma unroll
      for (int n = 0; n < 4; ++n) {
        const size_t cb = (size_t)(row0 + wr * 128 + m * 16 + cr) * ldc +
                          col0 + wc * 64 + n * 16 + cc;
#pragma unroll
        for (int j = 0; j < 4; ++j)
          C[cb + (size_t)j * ldc] = __float2bfloat16(acc[m][n][j]);
      }
  } else {
    float* C = (float*)Cp;
    float bv[4];
#pragma unroll
    for (int n = 0; n < 4; ++n) bv[n] = bias[col0 + wc * 64 + n * 16 + cc];
#pragma unroll
    for (int m = 0; m < 8; ++m)
#pragma unroll
      for (int n = 0; n < 4; ++n) {
        const size_t cb = (size_t)(row0 + wr * 128 + m * 16 + cr) * ldc +
                          col0 + wc * 64 + n * 16 + cc;
#pragma unroll
        for (int j = 0; j < 4; ++j)
          C[cb + (size_t)j * ldc] = acc[m][n][j] + bv[n];
      }
  }
}

// ---------------------------------------------------------------------------
// Fused q-softmax + context partials, s-split 8 (4x128-row chunks / block).
// grid (64, 8) x 256
// ---------------------------------------------------------------------------
__global__ __launch_bounds__(256) void ctxkvq_k(__hip_bfloat16* __restrict__ qkv,
                                                float* __restrict__ part,
                                                float* __restrict__ den) {
  __shared__ __hip_bfloat16 ldsb[2 * 8736];
  __hip_bfloat16* ekT = ldsb;
  __hip_bfloat16* vfT = ldsb + 8736;

  const int bh = blockIdx.x;
  const int sc = blockIdx.y;
  const int b = bh >> 4;
  const int h = bh & 15;
  const int t = threadIdx.x;

  const int rr = t >> 1;
  const int c0 = (t & 1) * 32;
  const int w = t >> 6, l = t & 63;
  const int lr = l & 15, hk = l >> 4;
  const int arow = w * 16 + lr;
  const int abase = arow * 136 + ((arow >> 5) & 1) * 32 + hk * 8;

  f32x4 acc[4];
#pragma unroll
  for (int n = 0; n < 4; ++n) acc[n] = (f32x4){0.f, 0.f, 0.f, 0.f};
  float denacc = 0.f;
  const int dd = t >> 2;
  const int dbase = dd * 136 + ((dd >> 5) & 1) * 32;

  for (int c = 0; c < 4; ++c) {
    const int n0 = sc * 512 + c * 128;
    const size_t base =
        (size_t)(b * TT + n0 + rr) * 3072 + 1024 + h * 64 + c0;
    int4 kq[4], vq[4];
#pragma unroll
    for (int i = 0; i < 4; ++i) {
      kq[i] = *(const int4*)(qkv + base + i * 8);
      vq[i] = *(const int4*)(qkv + base + 1024 + i * 8);
    }

    // fused q softmax for the same 128 rows (independent of k/v loads)
    {
      const int g8 = t >> 3;
      const int lc = (t & 7) * 8;
#pragma unroll
      for (int it = 0; it < 4; ++it) {
        const int r = it * 32 + g8;
        __hip_bfloat16* p =
            qkv + (size_t)(b * TT + n0 + r) * 3072 + h * 64 + lc;
        int4 raw = *(const int4*)p;
        const __hip_bfloat16* bp = (const __hip_bfloat16*)&raw;
        float v[8];
        float m = -1e30f;
#pragma unroll
        for (int j = 0; j < 8; ++j) {
          v[j] = __bfloat162float(bp[j]);
          m = fmaxf(m, v[j]);
        }
        m = fmaxf(m, __shfl_xor(m, 1));
        m = fmaxf(m, __shfl_xor(m, 2));
        m = fmaxf(m, __shfl_xor(m, 4));
        float sm = 0.f;
#pragma unroll
        for (int j = 0; j < 8; ++j) {
          v[j] = __expf(v[j] - m);
          sm += v[j];
        }
        sm += __shfl_xor(sm, 1);
        sm += __shfl_xor(sm, 2);
        sm += __shfl_xor(sm, 4);
        const float inv = 0.125f / sm;
        __hip_bfloat16 o[8] __attribute__((aligned(16)));
#pragma unroll
        for (int j = 0; j < 8; ++j) o[j] = __float2bfloat16(v[j] * inv);
        *(int4*)p = *(const int4*)o;
      }
    }

    __syncthreads();  // WAR: previous chunk's ekT/vfT reads complete
#pragma unroll
    for (int i = 0; i < 4; ++i) {
      const __hip_bfloat16* kp = (const __hip_bfloat16*)&kq[i];
      const __hip_bfloat16* vp = (const __hip_bfloat16*)&vq[i];
#pragma unroll
      for (int j = 0; j < 8; ++j) {
        const int cidx = c0 + i * 8 + j;
        const int off = cidx * 136 + ((cidx >> 5) & 1) * 32 + rr;
        ekT[off] = __float2bfloat16(__expf(__bfloat162float(kp[j])));
        vfT[off] = vp[j];
      }
    }
    __syncthreads();

#pragma unroll
    for (int ks = 0; ks < 4; ++ks) {
      bf16x8 af = *(const bf16x8*)(ekT + abase + ks * 32);
#pragma unroll
      for (int n = 0; n < 4; ++n) {
        const int brow = n * 16 + lr;
        bf16x8 bf = *(const bf16x8*)(vfT + brow * 136 +
                                     ((brow >> 5) & 1) * 32 + hk * 8 + ks * 32);
        acc[n] =
            __builtin_amdgcn_mfma_f32_16x16x32_bf16(af, bf, acc[n], 0, 0, 0);
      }
    }

    if ((t & 3) == 0) {
#pragma unroll
      for (int q8 = 0; q8 < 16; ++q8) {
        bf16x8 e8 = *(const bf16x8*)(ekT + dbase + q8 * 8);
        const __hip_bfloat16* ep = (const __hip_bfloat16*)&e8;
#pragma unroll
        for (int j = 0; j < 8; ++j) denacc += __bfloat162float(ep[j]);
      }
    }
  }

  float* pb = part + ((size_t)bh * 8 + sc) * 4096;
#pragma unroll
  for (int n = 0; n < 4; ++n)
#pragma unroll
    for (int j = 0; j < 4; ++j)
      pb[(w * 16 + hk * 4 + j) * 64 + n * 16 + lr] = acc[n][j];

  if ((t & 3) == 0) den[((size_t)bh * 8 + sc) * 64 + dd] = denacc;
}

// ---------------------------------------------------------------------------
// ctxb[bh][d][e] = bf16( (sum_s part) / (sum_s den[d]) ); grid (64,4) x 256
// ---------------------------------------------------------------------------
__global__ __launch_bounds__(256) void ctx_reduce_k(
    const float* __restrict__ part, const float* __restrict__ den,
    __hip_bfloat16* __restrict__ ctxb) {
  const int bh = blockIdx.x, q = blockIdx.y, t = threadIdx.x;
  const int idx = q * 1024 + t * 4;
  const int d = idx >> 6;
  float sden = 0.f;
  for (int s = 0; s < 8; ++s) sden += den[((size_t)bh * 8 + s) * 64 + d];
  float4 sv = {0.f, 0.f, 0.f, 0.f};
  const float* pb = part + (size_t)bh * 8 * 4096 + idx;
  for (int s = 0; s < 8; ++s) {
    float4 v = *(const float4*)(pb + (size_t)s * 4096);
    sv.x += v.x; sv.y += v.y; sv.z += v.z; sv.w += v.w;
  }
  const float di = 1.0f / sden;
  __hip_bfloat16 ob[4] __attribute__((aligned(8)));
  ob[0] = __float2bfloat16(sv.x * di);
  ob[1] = __float2bfloat16(sv.y * di);
  ob[2] = __float2bfloat16(sv.z * di);
  ob[3] = __float2bfloat16(sv.w * di);
  *(int2*)&ctxb[(size_t)bh * 4096 + idx] = *(const int2*)ob;
}

// ---------------------------------------------------------------------------
// WfT[b][n][k] = sum_e ctx[b][h(k)][k&63][e] * Wo[h*64+e][n]  (bf16, MFMA)
// grid (64 bh, 16 n-chunks) x 256 (4 waves x 16 rows)
// ---------------------------------------------------------------------------
__global__ __launch_bounds__(256) void wfuse_k(
    const __hip_bfloat16* __restrict__ WT,
    const __hip_bfloat16* __restrict__ ctxb, __hip_bfloat16* __restrict__ WfT) {
  const int bh = blockIdx.x;
  const int b = bh >> 4, h = bh & 15;
  const int t = threadIdx.x, w = t >> 6, l = t & 63;
  const int n1 = blockIdx.y * 64 + w * 16;
  const int lr = l & 15, hk = l >> 4;

  f32x4 acc[4];
#pragma unroll
  for (int n = 0; n < 4; ++n) acc[n] = (f32x4){0.f, 0.f, 0.f, 0.f};

  const __hip_bfloat16* Abase =
      WT + (size_t)(3072 + n1 + lr) * 1024 + h * 64 + hk * 8;
  const __hip_bfloat16* Bbase = ctxb + (size_t)bh * 4096 + hk * 8;

#pragma unroll
  for (int kk2 = 0; kk2 < 2; ++kk2) {
    bf16x8 af = *(const bf16x8*)(Abase + kk2 * 32);
#pragma unroll
    for (int n = 0; n < 4; ++n) {
      bf16x8 bf = *(const bf16x8*)(Bbase + (n * 16 + lr) * 64 + kk2 * 32);
      acc[n] = __builtin_amdgcn_mfma_f32_16x16x32_bf16(af, bf, acc[n], 0, 0, 0);
    }
  }

  __hip_bfloat16* W0 = WfT + ((size_t)b << 20) + (size_t)(n1 + hk * 4) * 1024 +
                       h * 64 + lr;
#pragma unroll
  for (int n = 0; n < 4; ++n)
#pragma unroll
    for (int j = 0; j < 4; ++j)
      W0[(size_t)j * 1024 + n * 16] = __float2bfloat16(acc[n][j]);
}

// ---------------------------------------------------------------------------
extern "C" void kernel_launch(void* const* d_in, const int* in_sizes, int n_in,
                              void* d_out, int out_size, void* d_ws,
                              size_t ws_size, hipStream_t stream) {
  const float* x = (const float*)d_in[0];
  const float* Wq = (const float*)d_in[1];
  const float* Wk = (const float*)d_in[2];
  const float* Wv = (const float*)d_in[3];
  const float* Wo = (const float*)d_in[4];
  const float* bo = (const float*)d_in[5];
  float* out = (float*)d_out;

  // ws: qkv bf16 [16384][3072] (96MB) | WT bf16 [4096][1024] (8MB)
  //     | den f32 (128KB) | ctxb bf16 (512KB) | WfT bf16 4x[1024][1024] (8MB)
  char* ws = (char*)d_ws;
  __hip_bfloat16* qkv = (__hip_bfloat16*)ws;
  __hip_bfloat16* WT = (__hip_bfloat16*)(ws + 100663296ull);
  float* den = (float*)(ws + 100663296ull + 8388608ull);
  __hip_bfloat16* ctxb =
      (__hip_bfloat16*)(ws + 100663296ull + 8388608ull + 524288ull);
  __hip_bfloat16* WfT =
      (__hip_bfloat16*)(ws + 100663296ull + 8388608ull + 1048576ull);
  // d_out doubles as scratch, fully overwritten by the final GEMM:
  //   [0,32MB) xb bf16; [32,40.4MB) part f32 [64][8][4096]
  __hip_bfloat16* xb = (__hip_bfloat16*)d_out;
  float* part = (float*)((char*)d_out + 33554432ull);

  const dim3 blk(256);

  // fused x->bf16 + W transpose
  prep_k<<<dim3(9216), blk, 0, stream>>>(x, Wq, Wk, Wv, Wo, xb, WT);

  // QKV projection — EXPERIMENT: 64KB-LDS dbuf (2 blocks/CU)
  mgemm6_k<0, 0><<<dim3(768), dim3(512), 0, stream>>>(xb, 1024, WT, nullptr,
                                                      qkv, 3072, 12);

  // fused q-softmax + context partials (MFMA), s-split 8
  ctxkvq_k<<<dim3(64, 8), blk, 0, stream>>>(qkv, part, den);
  ctx_reduce_k<<<dim3(64, 4), blk, 0, stream>>>(part, den, ctxb);
  wfuse_k<<<dim3(64, 16), blk, 0, stream>>>(WT, ctxb, WfT);

  // out = qs @ Wfused[b] + bo — CONTROL: champion mgemm3
  mgemm3_k<1, 1><<<dim3(256), dim3(512), 0, stream>>>(qkv, 3072, WfT, bo, out,
                                                      1024, 4);
}

// Round 14
// 189.445 us; speedup vs baseline: 1.0385x; 1.0385x over previous
//
#include <hip/hip_runtime.h>
#include <hip/hip_bf16.h>
#include <cstdint>
#include <cstddef>

#define BB 4
#define TT 4096
#define HH 16
#define NROWS 16384  // B*T

typedef __attribute__((ext_vector_type(8))) short bf16x8;
typedef __attribute__((ext_vector_type(4))) float f32x4;

__device__ __forceinline__ void gload_lds16(const void* g, void* l) {
  __builtin_amdgcn_global_load_lds(
      (const __attribute__((address_space(1))) void*)g,
      (__attribute__((address_space(3))) void*)l, 16, 0, 0);
}

template <int N>
__device__ __forceinline__ void wait_vmcnt() {
  if constexpr (N == 4)
    asm volatile("s_waitcnt vmcnt(4)" ::: "memory");
  else
    asm volatile("s_waitcnt vmcnt(0)" ::: "memory");
  __builtin_amdgcn_sched_barrier(0);
}

__device__ __forceinline__ void hbar() {
  asm volatile("s_barrier" ::: "memory");
  __builtin_amdgcn_sched_barrier(0);
}

// ---------------------------------------------------------------------------
// prep: fused x->bf16 conversion (blocks 0..8191) + W transpose (8192..9215)
// (r13-verified: saves ~1.5 us vs separate xconv+wconv launches)
// ---------------------------------------------------------------------------
__global__ __launch_bounds__(256) void prep_k(const float* __restrict__ x,
                                              const float* __restrict__ Wq,
                                              const float* __restrict__ Wk,
                                              const float* __restrict__ Wv,
                                              const float* __restrict__ Wo,
                                              __hip_bfloat16* __restrict__ xb,
                                              __hip_bfloat16* __restrict__ WT) {
  const int t = threadIdx.x;
  if (blockIdx.x < 8192) {
    const size_t i = ((size_t)blockIdx.x * 256 + t) * 8;
    float4 a = *(const float4*)&x[i];
    float4 b = *(const float4*)&x[i + 4];
    __hip_bfloat16 o[8] __attribute__((aligned(16)));
    o[0] = __float2bfloat16(a.x); o[1] = __float2bfloat16(a.y);
    o[2] = __float2bfloat16(a.z); o[3] = __float2bfloat16(a.w);
    o[4] = __float2bfloat16(b.x); o[5] = __float2bfloat16(b.y);
    o[6] = __float2bfloat16(b.z); o[7] = __float2bfloat16(b.w);
    *(int4*)&xb[i] = *(const int4*)o;
    return;
  }
  const int bid2 = blockIdx.x - 8192;
  const int which = bid2 >> 8;
  const int sub = bid2 & 255;
  const float* W = which == 0 ? Wq : which == 1 ? Wk : which == 2 ? Wv : Wo;
  __shared__ float tile[64][65];
  const int n0 = (sub & 15) * 64, k0 = (sub >> 4) * 64;
  const int r = t >> 2;
  const int cq = (t & 3) * 16;
#pragma unroll
  for (int i = 0; i < 4; ++i) {
    float4 v = *(const float4*)&W[(size_t)(k0 + r) * 1024 + n0 + cq + i * 4];
    tile[r][cq + i * 4 + 0] = v.x;
    tile[r][cq + i * 4 + 1] = v.y;
    tile[r][cq + i * 4 + 2] = v.z;
    tile[r][cq + i * 4 + 3] = v.w;
  }
  __syncthreads();
  __hip_bfloat16 ob[16] __attribute__((aligned(16)));
#pragma unroll
  for (int j = 0; j < 16; ++j) ob[j] = __float2bfloat16(tile[cq + j][r]);
  __hip_bfloat16* dst = WT + (size_t)(which * 1024 + n0 + r) * 1024 + k0 + cq;
  *(int4*)dst = *(const int4*)&ob[0];
  *(int4*)(dst + 8) = *(const int4*)&ob[8];
}

// ---------------------------------------------------------------------------
// MFMA bf16 GEMM, 256x256 tile, BK=64, double-buffered LDS, 4 phases/tile.
// ROUND-7 SCHEDULE VERBATIM — verified champion: 106 us QKV, FETCH 94.3 MB,
// MfmaUtil 43.8%, VGPR 100. Five restructures lost to it (r5 lane-map, r9
// ring-4, r11 phase-split, r13 64KB-dbuf occupancy; r6 layout was the one
// win, folded in). NO epilogue softmax (QSM correlates with +50% FETCH).
// PB: B pointer advances by 1M elems per 4096-row batch (fused Wo path).
// ---------------------------------------------------------------------------
template <int OMODE, int PB>
__global__ __launch_bounds__(512) void mgemm3_k(
    const __hip_bfloat16* __restrict__ A, int lda,
    const __hip_bfloat16* __restrict__ BT, const float* __restrict__ bias,
    void* __restrict__ Cp, int ldc, int gx) {
  __shared__ __hip_bfloat16 lds[2][32768];  // 128 KiB

  const int t = threadIdx.x;
  const int wid = t >> 6, l = t & 63;
  const int wr = wid >> 2, wc = wid & 3;

  const int nwg = gridDim.x;
  const int cpx = nwg >> 3;
  const int bid = blockIdx.x;
  const int swz = (bid & 7) * cpx + (bid >> 3);
  const int bx = swz % gx, by = swz / gx;
  const int row0 = by * 256, col0 = bx * 256;

  const __hip_bfloat16* BTb = PB ? BT + ((size_t)(row0 >> 12) << 20) : BT;

  const int sg = l >> 3;
  const int octp = ((l & 7) + sg) & 7;
  const int koct = octp & 3;
  const int srow = 2 * (wid * 16 + sg) + (octp >> 2);
  const __hip_bfloat16* As0 = A + (size_t)(row0 + srow) * lda + koct * 8;
  const __hip_bfloat16* Bs0 = BTb + (size_t)(col0 + srow) * 1024 + koct * 8;

  f32x4 acc[8][4];
#pragma unroll
  for (int m = 0; m < 8; ++m)
#pragma unroll
    for (int n = 0; n < 4; ++n) acc[m][n] = (f32x4){0.f, 0.f, 0.f, 0.f};

  const int lr = l & 15, hk = l >> 4;
  const int slot = (((lr & 1) << 2) + hk - (lr >> 1)) & 7;
  const int rdo = (lr >> 1) * 64 + slot * 8;

  auto stageA = [&](int tn, int c) {
    __hip_bfloat16* d = &lds[tn & 1][c * 8192 + wid * 1024];
    const __hip_bfloat16* s = As0 + tn * 64 + c * 32;
    gload_lds16(s, d);
    gload_lds16(s + (size_t)16 * lda, d + 512);
  };
  auto stageB = [&](int tn, int c) {
    __hip_bfloat16* d = &lds[tn & 1][16384 + c * 8192 + wid * 1024];
    const __hip_bfloat16* s = Bs0 + tn * 64 + c * 32;
    gload_lds16(s, d);
    gload_lds16(s + (size_t)16 * 1024, d + 512);
  };

  stageA(0, 0); stageB(0, 0); stageA(0, 1); stageB(0, 1);

  const __hip_bfloat16* sb = &lds[0][0];
  for (int tn = 0; tn < 16; ++tn) {
    const int bufo = (tn & 1) * 32768;
    const bool pre = tn < 15;
    bf16x8 bfv[4], afv[4];

    // ===== kstep 0 =====
    wait_vmcnt<4>();
    hbar();
    if (pre) stageA(tn + 1, 0);
#pragma unroll
    for (int n = 0; n < 4; ++n)
      bfv[n] = *(const bf16x8*)(sb + bufo + 16384 + wc * 2048 + n * 512 + rdo);
#pragma unroll
    for (int j = 0; j < 4; ++j)
      afv[j] = *(const bf16x8*)(sb + bufo + wr * 4096 + j * 512 + rdo);
    __builtin_amdgcn_s_setprio(1);
#pragma unroll
    for (int j = 0; j < 4; ++j)
#pragma unroll
      for (int n = 0; n < 4; ++n)
        acc[j][n] = __builtin_amdgcn_mfma_f32_16x16x32_bf16(afv[j], bfv[n],
                                                            acc[j][n], 0, 0, 0);
    __builtin_amdgcn_s_setprio(0);
    if (pre) stageB(tn + 1, 0);
#pragma unroll
    for (int j = 0; j < 4; ++j)
      afv[j] = *(const bf16x8*)(sb + bufo + wr * 4096 + 2048 + j * 512 + rdo);
    __builtin_amdgcn_s_setprio(1);
#pragma unroll
    for (int j = 0; j < 4; ++j)
#pragma unroll
      for (int n = 0; n < 4; ++n)
        acc[4 + j][n] = __builtin_amdgcn_mfma_f32_16x16x32_bf16(
            afv[j], bfv[n], acc[4 + j][n], 0, 0, 0);
    __builtin_amdgcn_s_setprio(0);

    // ===== kstep 1 =====
    if (pre)
      wait_vmcnt<4>();
    else
      wait_vmcnt<0>();
    hbar();
    if (pre) stageA(tn + 1, 1);
#pragma unroll
    for (int n = 0; n < 4; ++n)
      bfv[n] = *(const bf16x8*)(sb + bufo + 8192 + 16384 + wc * 2048 +
                                n * 512 + rdo);
#pragma unroll
    for (int j = 0; j < 4; ++j)
      afv[j] = *(const bf16x8*)(sb + bufo + 8192 + wr * 4096 + j * 512 + rdo);
    __builtin_amdgcn_s_setprio(1);
#pragma unroll
    for (int j = 0; j < 4; ++j)
#pragma unroll
      for (int n = 0; n < 4; ++n)
        acc[j][n] = __builtin_amdgcn_mfma_f32_16x16x32_bf16(afv[j], bfv[n],
                                                            acc[j][n], 0, 0, 0);
    __builtin_amdgcn_s_setprio(0);
    if (pre) stageB(tn + 1, 1);
#pragma unroll
    for (int j = 0; j < 4; ++j)
      afv[j] = *(const bf16x8*)(sb + bufo + 8192 + wr * 4096 + 2048 + j * 512 +
                                rdo);
    __builtin_amdgcn_s_setprio(1);
#pragma unroll
    for (int j = 0; j < 4; ++j)
#pragma unroll
      for (int n = 0; n < 4; ++n)
        acc[4 + j][n] = __builtin_amdgcn_mfma_f32_16x16x32_bf16(
            afv[j], bfv[n], acc[4 + j][n], 0, 0, 0);
    __builtin_amdgcn_s_setprio(0);
  }

  const int cr = hk * 4;
  const int cc = lr;
  if constexpr (OMODE == 0) {
    __hip_bfloat16* C = (__hip_bfloat16*)Cp;
#pragma unroll
    for (int m = 0; m < 8; ++m)
#pragma unroll
      for (int n = 0; n < 4; ++n) {
        const size_t cb = (size_t)(row0 + wr * 128 + m * 16 + cr) * ldc +
                          col0 + wc * 64 + n * 16 + cc;
#pragma unroll
        for (int j = 0; j < 4; ++j)
          C[cb + (size_t)j * ldc] = __float2bfloat16(acc[m][n][j]);
      }
  } else {
    float* C = (float*)Cp;
    float bv[4];
#pragma unroll
    for (int n = 0; n < 4; ++n) bv[n] = bias[col0 + wc * 64 + n * 16 + cc];
#pragma unroll
    for (int m = 0; m < 8; ++m)
#pragma unroll
      for (int n = 0; n < 4; ++n) {
        const size_t cb = (size_t)(row0 + wr * 128 + m * 16 + cr) * ldc +
                          col0 + wc * 64 + n * 16 + cc;
#pragma unroll
        for (int j = 0; j < 4; ++j)
          C[cb + (size_t)j * ldc] = acc[m][n][j] + bv[n];
      }
  }
}

// ---------------------------------------------------------------------------
// Fused q-softmax + context partials, s-split 8 (4x128-row chunks / block).
// grid (64, 8) x 256  — at its 128 MB HBM floor (~20 us).
// ---------------------------------------------------------------------------
__global__ __launch_bounds__(256) void ctxkvq_k(__hip_bfloat16* __restrict__ qkv,
                                                float* __restrict__ part,
                                                float* __restrict__ den) {
  __shared__ __hip_bfloat16 ldsb[2 * 8736];
  __hip_bfloat16* ekT = ldsb;
  __hip_bfloat16* vfT = ldsb + 8736;

  const int bh = blockIdx.x;
  const int sc = blockIdx.y;
  const int b = bh >> 4;
  const int h = bh & 15;
  const int t = threadIdx.x;

  const int rr = t >> 1;
  const int c0 = (t & 1) * 32;
  const int w = t >> 6, l = t & 63;
  const int lr = l & 15, hk = l >> 4;
  const int arow = w * 16 + lr;
  const int abase = arow * 136 + ((arow >> 5) & 1) * 32 + hk * 8;

  f32x4 acc[4];
#pragma unroll
  for (int n = 0; n < 4; ++n) acc[n] = (f32x4){0.f, 0.f, 0.f, 0.f};
  float denacc = 0.f;
  const int dd = t >> 2;
  const int dbase = dd * 136 + ((dd >> 5) & 1) * 32;

  for (int c = 0; c < 4; ++c) {
    const int n0 = sc * 512 + c * 128;
    const size_t base =
        (size_t)(b * TT + n0 + rr) * 3072 + 1024 + h * 64 + c0;
    int4 kq[4], vq[4];
#pragma unroll
    for (int i = 0; i < 4; ++i) {
      kq[i] = *(const int4*)(qkv + base + i * 8);
      vq[i] = *(const int4*)(qkv + base + 1024 + i * 8);
    }

    // fused q softmax for the same 128 rows (independent of k/v loads)
    {
      const int g8 = t >> 3;
      const int lc = (t & 7) * 8;
#pragma unroll
      for (int it = 0; it < 4; ++it) {
        const int r = it * 32 + g8;
        __hip_bfloat16* p =
            qkv + (size_t)(b * TT + n0 + r) * 3072 + h * 64 + lc;
        int4 raw = *(const int4*)p;
        const __hip_bfloat16* bp = (const __hip_bfloat16*)&raw;
        float v[8];
        float m = -1e30f;
#pragma unroll
        for (int j = 0; j < 8; ++j) {
          v[j] = __bfloat162float(bp[j]);
          m = fmaxf(m, v[j]);
        }
        m = fmaxf(m, __shfl_xor(m, 1));
        m = fmaxf(m, __shfl_xor(m, 2));
        m = fmaxf(m, __shfl_xor(m, 4));
        float sm = 0.f;
#pragma unroll
        for (int j = 0; j < 8; ++j) {
          v[j] = __expf(v[j] - m);
          sm += v[j];
        }
        sm += __shfl_xor(sm, 1);
        sm += __shfl_xor(sm, 2);
        sm += __shfl_xor(sm, 4);
        const float inv = 0.125f / sm;
        __hip_bfloat16 o[8] __attribute__((aligned(16)));
#pragma unroll
        for (int j = 0; j < 8; ++j) o[j] = __float2bfloat16(v[j] * inv);
        *(int4*)p = *(const int4*)o;
      }
    }

    __syncthreads();  // WAR: previous chunk's ekT/vfT reads complete
#pragma unroll
    for (int i = 0; i < 4; ++i) {
      const __hip_bfloat16* kp = (const __hip_bfloat16*)&kq[i];
      const __hip_bfloat16* vp = (const __hip_bfloat16*)&vq[i];
#pragma unroll
      for (int j = 0; j < 8; ++j) {
        const int cidx = c0 + i * 8 + j;
        const int off = cidx * 136 + ((cidx >> 5) & 1) * 32 + rr;
        ekT[off] = __float2bfloat16(__expf(__bfloat162float(kp[j])));
        vfT[off] = vp[j];
      }
    }
    __syncthreads();

#pragma unroll
    for (int ks = 0; ks < 4; ++ks) {
      bf16x8 af = *(const bf16x8*)(ekT + abase + ks * 32);
#pragma unroll
      for (int n = 0; n < 4; ++n) {
        const int brow = n * 16 + lr;
        bf16x8 bf = *(const bf16x8*)(vfT + brow * 136 +
                                     ((brow >> 5) & 1) * 32 + hk * 8 + ks * 32);
        acc[n] =
            __builtin_amdgcn_mfma_f32_16x16x32_bf16(af, bf, acc[n], 0, 0, 0);
      }
    }

    if ((t & 3) == 0) {
#pragma unroll
      for (int q8 = 0; q8 < 16; ++q8) {
        bf16x8 e8 = *(const bf16x8*)(ekT + dbase + q8 * 8);
        const __hip_bfloat16* ep = (const __hip_bfloat16*)&e8;
#pragma unroll
        for (int j = 0; j < 8; ++j) denacc += __bfloat162float(ep[j]);
      }
    }
  }

  float* pb = part + ((size_t)bh * 8 + sc) * 4096;
#pragma unroll
  for (int n = 0; n < 4; ++n)
#pragma unroll
    for (int j = 0; j < 4; ++j)
      pb[(w * 16 + hk * 4 + j) * 64 + n * 16 + lr] = acc[n][j];

  if ((t & 3) == 0) den[((size_t)bh * 8 + sc) * 64 + dd] = denacc;
}

// ---------------------------------------------------------------------------
// ctxb[bh][d][e] = bf16( (sum_s part) / (sum_s den[d]) ); grid (64,4) x 256
// ---------------------------------------------------------------------------
__global__ __launch_bounds__(256) void ctx_reduce_k(
    const float* __restrict__ part, const float* __restrict__ den,
    __hip_bfloat16* __restrict__ ctxb) {
  const int bh = blockIdx.x, q = blockIdx.y, t = threadIdx.x;
  const int idx = q * 1024 + t * 4;
  const int d = idx >> 6;
  float sden = 0.f;
  for (int s = 0; s < 8; ++s) sden += den[((size_t)bh * 8 + s) * 64 + d];
  float4 sv = {0.f, 0.f, 0.f, 0.f};
  const float* pb = part + (size_t)bh * 8 * 4096 + idx;
  for (int s = 0; s < 8; ++s) {
    float4 v = *(const float4*)(pb + (size_t)s * 4096);
    sv.x += v.x; sv.y += v.y; sv.z += v.z; sv.w += v.w;
  }
  const float di = 1.0f / sden;
  __hip_bfloat16 ob[4] __attribute__((aligned(8)));
  ob[0] = __float2bfloat16(sv.x * di);
  ob[1] = __float2bfloat16(sv.y * di);
  ob[2] = __float2bfloat16(sv.z * di);
  ob[3] = __float2bfloat16(sv.w * di);
  *(int2*)&ctxb[(size_t)bh * 4096 + idx] = *(const int2*)ob;
}

// ---------------------------------------------------------------------------
// WfT[b][n][k] = sum_e ctx[b][h(k)][k&63][e] * Wo[h*64+e][n]  (bf16, MFMA)
// grid (64 bh, 16 n-chunks) x 256 (4 waves x 16 rows)
// ---------------------------------------------------------------------------
__global__ __launch_bounds__(256) void wfuse_k(
    const __hip_bfloat16* __restrict__ WT,
    const __hip_bfloat16* __restrict__ ctxb, __hip_bfloat16* __restrict__ WfT) {
  const int bh = blockIdx.x;
  const int b = bh >> 4, h = bh & 15;
  const int t = threadIdx.x, w = t >> 6, l = t & 63;
  const int n1 = blockIdx.y * 64 + w * 16;
  const int lr = l & 15, hk = l >> 4;

  f32x4 acc[4];
#pragma unroll
  for (int n = 0; n < 4; ++n) acc[n] = (f32x4){0.f, 0.f, 0.f, 0.f};

  const __hip_bfloat16* Abase =
      WT + (size_t)(3072 + n1 + lr) * 1024 + h * 64 + hk * 8;
  const __hip_bfloat16* Bbase = ctxb + (size_t)bh * 4096 + hk * 8;

#pragma unroll
  for (int kk2 = 0; kk2 < 2; ++kk2) {
    bf16x8 af = *(const bf16x8*)(Abase + kk2 * 32);
#pragma unroll
    for (int n = 0; n < 4; ++n) {
      bf16x8 bf = *(const bf16x8*)(Bbase + (n * 16 + lr) * 64 + kk2 * 32);
      acc[n] = __builtin_amdgcn_mfma_f32_16x16x32_bf16(af, bf, acc[n], 0, 0, 0);
    }
  }

  __hip_bfloat16* W0 = WfT + ((size_t)b << 20) + (size_t)(n1 + hk * 4) * 1024 +
                       h * 64 + lr;
#pragma unroll
  for (int n = 0; n < 4; ++n)
#pragma unroll
    for (int j = 0; j < 4; ++j)
      W0[(size_t)j * 1024 + n * 16] = __float2bfloat16(acc[n][j]);
}

// ---------------------------------------------------------------------------
extern "C" void kernel_launch(void* const* d_in, const int* in_sizes, int n_in,
                              void* d_out, int out_size, void* d_ws,
                              size_t ws_size, hipStream_t stream) {
  const float* x = (const float*)d_in[0];
  const float* Wq = (const float*)d_in[1];
  const float* Wk = (const float*)d_in[2];
  const float* Wv = (const float*)d_in[3];
  const float* Wo = (const float*)d_in[4];
  const float* bo = (const float*)d_in[5];
  float* out = (float*)d_out;

  // ws: qkv bf16 [16384][3072] (96MB) | WT bf16 [4096][1024] (8MB)
  //     | den f32 (128KB) | ctxb bf16 (512KB) | WfT bf16 4x[1024][1024] (8MB)
  char* ws = (char*)d_ws;
  __hip_bfloat16* qkv = (__hip_bfloat16*)ws;
  __hip_bfloat16* WT = (__hip_bfloat16*)(ws + 100663296ull);
  float* den = (float*)(ws + 100663296ull + 8388608ull);
  __hip_bfloat16* ctxb =
      (__hip_bfloat16*)(ws + 100663296ull + 8388608ull + 524288ull);
  __hip_bfloat16* WfT =
      (__hip_bfloat16*)(ws + 100663296ull + 8388608ull + 1048576ull);
  // d_out doubles as scratch, fully overwritten by the final GEMM:
  //   [0,32MB) xb bf16; [32,40.4MB) part f32 [64][8][4096]
  __hip_bfloat16* xb = (__hip_bfloat16*)d_out;
  float* part = (float*)((char*)d_out + 33554432ull);

  const dim3 blk(256);

  // fused x->bf16 + W transpose
  prep_k<<<dim3(9216), blk, 0, stream>>>(x, Wq, Wk, Wv, Wo, xb, WT);

  // QKV projection — champion mgemm3
  mgemm3_k<0, 0><<<dim3(768), dim3(512), 0, stream>>>(xb, 1024, WT, nullptr,
                                                      qkv, 3072, 12);

  // fused q-softmax + context partials (MFMA), s-split 8
  ctxkvq_k<<<dim3(64, 8), blk, 0, stream>>>(qkv, part, den);
  ctx_reduce_k<<<dim3(64, 4), blk, 0, stream>>>(part, den, ctxb);
  wfuse_k<<<dim3(64, 16), blk, 0, stream>>>(WT, ctxb, WfT);

  // out = qs @ Wfused[b] + bo — champion mgemm3
  mgemm3_k<1, 1><<<dim3(256), dim3(512), 0, stream>>>(qkv, 3072, WfT, bo, out,
                                                      1024, 4);
}